// Round 1
// baseline (357.465 us; speedup 1.0000x reference)
//
#include <hip/hip_runtime.h>
#include <stdint.h>
#include <stddef.h>

#define C_INC 320
#define KREAL 2880
#define KPAD  2944
#define OUT_F 384
#define RANK  32
#define HH    64
#define WW    64
#define LTOK  4096
#define NTOK  16384
#define NCH   8          // channel chunks for lora down
#define CCHUNK 40        // 320/8

typedef int vi4 __attribute__((ext_vector_type(4)));

// ---------------- kernel: quantize weights per output row ----------------
__global__ __launch_bounds__(256) void kq_w(const float* __restrict__ w,
                                            int8_t* __restrict__ qw,
                                            float* __restrict__ sw) {
    int o = blockIdx.x;
    const float* row = w + (size_t)o * KPAD;
    float m = 0.f;
    for (int k = threadIdx.x; k < KPAD; k += 256) m = fmaxf(m, fabsf(row[k]));
    #pragma unroll
    for (int off = 32; off > 0; off >>= 1) m = fmaxf(m, __shfl_down(m, off, 64));
    __shared__ float red[4];
    __shared__ float sval;
    int wv = threadIdx.x >> 6;
    if ((threadIdx.x & 63) == 0) red[wv] = m;
    __syncthreads();
    if (threadIdx.x == 0) {
        float mm = fmaxf(fmaxf(red[0], red[1]), fmaxf(red[2], red[3]));
        sval = fmaxf(mm / 7.0f, 1e-8f);
        sw[o] = sval;
    }
    __syncthreads();
    float s = sval;
    for (int k = threadIdx.x; k < KPAD; k += 256) {
        float q = rintf(row[k] / s);          // IEEE div + round-half-even, matches np
        q = fminf(fmaxf(q, -8.f), 7.f);
        qw[(size_t)o * KPAD + k] = (int8_t)q;
    }
}

// ---------------- kernel: per-pixel channel abs-max ----------------
__global__ __launch_bounds__(256) void k_chmax(const float* __restrict__ x,
                                               float* __restrict__ mbuf) {
    int p = blockIdx.x * 256 + threadIdx.x;   // 0..16383
    int n = p >> 12, hw = p & 4095;
    const float* base = x + ((size_t)n * C_INC) * (HH * WW) + hw;
    float m = 0.f;
    #pragma unroll 4
    for (int c = 0; c < C_INC; ++c) m = fmaxf(m, fabsf(base[(size_t)c * (HH * WW)]));
    mbuf[p] = m;
}

// ---------------- kernel: sx = max over 3x3 neighborhood / 7 ----------------
__global__ __launch_bounds__(256) void k_sx(const float* __restrict__ mbuf,
                                            float* __restrict__ sx) {
    int p = blockIdx.x * 256 + threadIdx.x;
    int n = p >> 12, hw = p & 4095;
    int h = hw >> 6, w = hw & 63;
    float m = 0.f;
    #pragma unroll
    for (int di = -1; di <= 1; ++di)
        #pragma unroll
        for (int dj = -1; dj <= 1; ++dj) {
            int hh = h + di, ww = w + dj;
            if ((unsigned)hh < (unsigned)HH && (unsigned)ww < (unsigned)WW)
                m = fmaxf(m, mbuf[(n << 12) + (hh << 6) + ww]);
        }
    sx[p] = fmaxf(m / 7.0f, 1e-8f);
}

// ---------------- kernel: quantize activations into int8 im2col ----------------
__global__ __launch_bounds__(256) void k_qx(const float* __restrict__ x,
                                            const float* __restrict__ sx,
                                            int8_t* __restrict__ qx) {
    int t = blockIdx.x;                 // token
    int n = t >> 12, hw = t & 4095;
    int h = hw >> 6, w = hw & 63;
    float s = sx[t];
    const float* xb = x + (size_t)n * C_INC * (HH * WW);
    int8_t* qb = qx + (size_t)t * KPAD;
    for (int k = threadIdx.x; k < KPAD; k += 256) {
        float v = 0.f;
        if (k < KREAL) {
            int c = k / 9, u = k - c * 9;
            int di = u / 3, dj = u - di * 3;
            int hh = h + di - 1, ww = w + dj - 1;
            if ((unsigned)hh < (unsigned)HH && (unsigned)ww < (unsigned)WW)
                v = xb[(size_t)c * (HH * WW) + (hh << 6) + ww];
        }
        float q = rintf(v / s);          // IEEE div for exact match
        q = fminf(fmaxf(q, -8.f), 7.f);
        qb[k] = (int8_t)q;
    }
}

// ---------------- kernel: lora down-projection r = xu @ pd (fp32, channel-split) ----------------
__global__ __launch_bounds__(256) void k_lora_down(const float* __restrict__ x,
                                                   const float* __restrict__ pd,
                                                   float* __restrict__ rpart) {
    int pb = blockIdx.x & 63;       // 64 pixel blocks of 256 pixels
    int cc = blockIdx.x >> 6;       // 0..7 channel chunk
    int p = pb * 256 + threadIdx.x;
    int n = p >> 12, hw = p & 4095;
    int h = hw >> 6, w = hw & 63;
    const float* xb = x + (size_t)n * C_INC * (HH * WW);
    int off[9]; bool valid[9];
    #pragma unroll
    for (int u = 0; u < 9; ++u) {
        int di = u / 3, dj = u - (u / 3) * 3;
        int hh = h + di - 1, ww = w + dj - 1;
        valid[u] = ((unsigned)hh < (unsigned)HH) && ((unsigned)ww < (unsigned)WW);
        off[u] = (hh << 6) + ww;
    }
    float acc[RANK];
    #pragma unroll
    for (int j = 0; j < RANK; ++j) acc[j] = 0.f;
    int c0 = cc * CCHUNK;
    for (int c = c0; c < c0 + CCHUNK; ++c) {
        const float* xc = xb + (size_t)c * (HH * WW);
        float v[9];
        #pragma unroll
        for (int u = 0; u < 9; ++u) v[u] = valid[u] ? xc[off[u]] : 0.f;
        const float* pr = pd + (size_t)(c * 9) * RANK;
        #pragma unroll
        for (int u = 0; u < 9; ++u) {
            #pragma unroll
            for (int j = 0; j < RANK; ++j)
                acc[j] = fmaf(v[u], pr[u * RANK + j], acc[j]);
        }
    }
    float* rp = rpart + ((size_t)cc * NTOK + p) * RANK;
    #pragma unroll
    for (int j = 0; j < RANK; ++j) rp[j] = acc[j];
}

// ---------------- kernel: int8 MFMA GEMM, writes y_q * sx * sw ----------------
__global__ __launch_bounds__(256) void k_gemm(const int8_t* __restrict__ qx,
                                              const int8_t* __restrict__ qw,
                                              const float* __restrict__ sx,
                                              const float* __restrict__ sw,
                                              float* __restrict__ out) {
    __shared__ int8_t lsA[128 * 80];   // row stride 80 B (pad 16) -> <=2-way LDS conflicts
    __shared__ int8_t lsB[128 * 80];
    int tid = threadIdx.x;
    int m0 = blockIdx.x * 128;
    int n0 = blockIdx.y * 128;
    int wid = tid >> 6, lane = tid & 63;
    int wr = wid >> 1, wc = wid & 1;
    int lg = lane >> 4, lr = lane & 15;
    vi4 acc[4][4];
    #pragma unroll
    for (int i = 0; i < 4; ++i)
        #pragma unroll
        for (int j = 0; j < 4; ++j) acc[i][j] = (vi4)0;

    for (int kk = 0; kk < KPAD; kk += 64) {
        #pragma unroll
        for (int i = 0; i < 2; ++i) {
            int chunk = tid + i * 256;        // 0..511 chunks of 16B
            int row = chunk >> 2, c4 = chunk & 3;
            *(vi4*)&lsA[row * 80 + c4 * 16] =
                *(const vi4*)&qx[(size_t)(m0 + row) * KPAD + kk + c4 * 16];
            *(vi4*)&lsB[row * 80 + c4 * 16] =
                *(const vi4*)&qw[(size_t)(n0 + row) * KPAD + kk + c4 * 16];
        }
        __syncthreads();
        vi4 af[4], bf[4];
        #pragma unroll
        for (int mi = 0; mi < 4; ++mi)
            af[mi] = *(vi4*)&lsA[(wr * 64 + mi * 16 + lr) * 80 + lg * 16];
        #pragma unroll
        for (int ni = 0; ni < 4; ++ni)
            bf[ni] = *(vi4*)&lsB[(wc * 64 + ni * 16 + lr) * 80 + lg * 16];
        #pragma unroll
        for (int mi = 0; mi < 4; ++mi)
            #pragma unroll
            for (int ni = 0; ni < 4; ++ni)
                acc[mi][ni] = __builtin_amdgcn_mfma_i32_16x16x64_i8(af[mi], bf[ni], acc[mi][ni], 0, 0, 0);
        __syncthreads();
    }

    // epilogue: out = (acc * sx) * sw   (C/D: col=lane&15, row=(lane>>4)*4+reg)
    float swv[4];
    #pragma unroll
    for (int ni = 0; ni < 4; ++ni) swv[ni] = sw[n0 + wc * 64 + ni * 16 + lr];
    #pragma unroll
    for (int mi = 0; mi < 4; ++mi) {
        int rbase = m0 + wr * 64 + mi * 16 + lg * 4;
        #pragma unroll
        for (int r = 0; r < 4; ++r) {
            int row = rbase + r;
            float sxv = sx[row];
            #pragma unroll
            for (int ni = 0; ni < 4; ++ni) {
                int col = n0 + wc * 64 + ni * 16 + lr;
                out[(size_t)row * OUT_F + col] = ((float)acc[mi][ni][r] * sxv) * swv[ni];
            }
        }
    }
}

// ---------------- kernel: epilogue out += r @ up + bias ----------------
__global__ __launch_bounds__(384) void k_epi(float* __restrict__ out,
                                             const float* __restrict__ rpart,
                                             const float* __restrict__ up,
                                             const float* __restrict__ bias) {
    __shared__ float upl[RANK * OUT_F];   // 48 KB
    __shared__ float rs[32][RANK];        // 4 KB
    int tid = threadIdx.x;                // 0..383
    for (int i = tid; i < RANK * OUT_F; i += 384) upl[i] = up[i];
    int t0 = blockIdx.x * 32;
    for (int i = tid; i < 32 * RANK; i += 384) {
        int tt = i >> 5, j = i & 31;
        float s = 0.f;
        #pragma unroll
        for (int cc = 0; cc < NCH; ++cc)
            s += rpart[((size_t)cc * NTOK + t0 + tt) * RANK + j];
        rs[tt][j] = s;
    }
    __syncthreads();
    int o = tid;
    float b = bias[o];
    for (int tt = 0; tt < 32; ++tt) {
        int t = t0 + tt;
        float acc = out[(size_t)t * OUT_F + o];
        float l = 0.f;
        #pragma unroll
        for (int j = 0; j < RANK; ++j) l = fmaf(rs[tt][j], upl[j * OUT_F + o], l);
        out[(size_t)t * OUT_F + o] = acc + l + b;
    }
}

extern "C" void kernel_launch(void* const* d_in, const int* in_sizes, int n_in,
                              void* d_out, int out_size, void* d_ws, size_t ws_size,
                              hipStream_t stream) {
    const float* x    = (const float*)d_in[0];   // (4,320,64,64)
    const float* w    = (const float*)d_in[1];   // (384,2944)
    const float* pd   = (const float*)d_in[2];   // (2944,32)
    const float* pu   = (const float*)d_in[3];   // (32,384)
    const float* bias = (const float*)d_in[4];   // (384,)
    float* out = (float*)d_out;                  // (4,4096,384) fp32

    char* ws = (char*)d_ws;
    int8_t* qw    = (int8_t*)(ws + 0);           // 384*2944        = 1,130,496
    float*  sw    = (float*) (ws + 1130496);     // 384*4           = 1,536
    float*  mb    = (float*) (ws + 1132032);     // 16384*4         = 65,536
    float*  sx    = (float*) (ws + 1197568);     // 16384*4         = 65,536
    int8_t* qx    = (int8_t*)(ws + 1263104);     // 16384*2944      = 48,234,496
    float*  rpart = (float*) (ws + 49497600);    // 8*16384*32*4    = 16,777,216  (end ~66.3 MB)

    hipLaunchKernelGGL(kq_w,        dim3(OUT_F),   dim3(256), 0, stream, w, qw, sw);
    hipLaunchKernelGGL(k_chmax,     dim3(64),      dim3(256), 0, stream, x, mb);
    hipLaunchKernelGGL(k_sx,        dim3(64),      dim3(256), 0, stream, mb, sx);
    hipLaunchKernelGGL(k_qx,        dim3(NTOK),    dim3(256), 0, stream, x, sx, qx);
    hipLaunchKernelGGL(k_lora_down, dim3(64 * NCH),dim3(256), 0, stream, x, pd, rpart);
    hipLaunchKernelGGL(k_gemm,      dim3(128, 3),  dim3(256), 0, stream, qx, qw, sx, sw, out);
    hipLaunchKernelGGL(k_epi,       dim3(512),     dim3(384), 0, stream, out, rpart, pu, bias);
}

// Round 4
// 282.095 us; speedup vs baseline: 1.2672x; 1.2672x over previous
//
#include <hip/hip_runtime.h>
#include <hip/hip_fp16.h>
#include <stdint.h>
#include <stddef.h>

#define C_INC 320
#define KREAL 2880
#define KPAD  2944
#define OUT_F 384
#define RANK  32
#define HH    64
#define WW    64
#define NTOK  16384
#define NCH   16         // channel chunks for fused kernel
#define CCH   20         // channels per chunk (16*20=320)
#define KCH   180        // k per chunk (CCH*9)
#define QSTR  116        // qbuf row stride bytes (12ch*9=108 +8 pad)

typedef int vi4 __attribute__((ext_vector_type(4)));

// ---------------- quantize weights per output row (R1 verbatim) ----------------
__global__ __launch_bounds__(256) void kq_w(const float* __restrict__ w,
                                            int8_t* __restrict__ qw,
                                            float* __restrict__ sw) {
    int o = blockIdx.x;
    const float* row = w + (size_t)o * KPAD;
    float m = 0.f;
    for (int k = threadIdx.x; k < KPAD; k += 256) m = fmaxf(m, fabsf(row[k]));
    #pragma unroll
    for (int off = 32; off > 0; off >>= 1) m = fmaxf(m, __shfl_down(m, off, 64));
    __shared__ float red[4];
    __shared__ float sval;
    if ((threadIdx.x & 63) == 0) red[threadIdx.x >> 6] = m;
    __syncthreads();
    if (threadIdx.x == 0) {
        float mm = fmaxf(fmaxf(red[0], red[1]), fmaxf(red[2], red[3]));
        sval = fmaxf(mm / 7.0f, 1e-8f);
        sw[o] = sval;
    }
    __syncthreads();
    float s = sval;
    for (int k = threadIdx.x; k < KPAD; k += 256) {
        float q = rintf(row[k] / s);          // IEEE div + RNE, matches np
        q = fminf(fmaxf(q, -8.f), 7.f);
        qw[(size_t)o * KPAD + k] = (int8_t)q;
    }
}

// ---------------- per-pixel channel abs-max (R1 verbatim) ----------------
__global__ __launch_bounds__(256) void k_chmax(const float* __restrict__ x,
                                               float* __restrict__ mbuf) {
    int p = blockIdx.x * 256 + threadIdx.x;   // 0..16383
    int n = p >> 12, hw = p & 4095;
    const float* base = x + ((size_t)n * C_INC) * (HH * WW) + hw;
    float m = 0.f;
    #pragma unroll 4
    for (int c = 0; c < C_INC; ++c) m = fmaxf(m, fabsf(base[(size_t)c * (HH * WW)]));
    mbuf[p] = m;
}

// ---------------- sx = max over 3x3 neighborhood / 7 (R1 verbatim) ----------------
__global__ __launch_bounds__(256) void k_sx(const float* __restrict__ mbuf,
                                            float* __restrict__ sx) {
    int p = blockIdx.x * 256 + threadIdx.x;
    int n = p >> 12, hw = p & 4095;
    int h = hw >> 6, w = hw & 63;
    float m = 0.f;
    #pragma unroll
    for (int di = -1; di <= 1; ++di)
        #pragma unroll
        for (int dj = -1; dj <= 1; ++dj) {
            int hh = h + di, ww = w + dj;
            if ((unsigned)hh < (unsigned)HH && (unsigned)ww < (unsigned)WW)
                m = fmaxf(m, mbuf[(n << 12) + (hh << 6) + ww]);
        }
    sx[p] = fmaxf(m / 7.0f, 1e-8f);
}

// ---------------- fused im2col quantize + LoRA down-projection ----------------
// grid (64, 16): blockIdx.x = (n, h/4), blockIdx.y = channel chunk.
// One wave per image row (lane = w). Neighbors via DIRECT predicated global
// loads (NO shfl: a shfl in a divergent ternary arm may read an exec-masked
// source lane -> returns 0 on gfx9; that was R2/R3's w=1/w=62 corruption).
// The +-1-shifted loads hit the same L1 lines as the coalesced row loads.
__global__ __launch_bounds__(256) void k_fused(const float* __restrict__ x,
                                               const float* __restrict__ pd,
                                               const float* __restrict__ sx,
                                               int8_t* __restrict__ qx,
                                               __half* __restrict__ rpart) {
    __shared__ float  pdl[KCH * RANK];     // 23040 B
    __shared__ int8_t qbuf[256 * QSTR];    // 29696 B
    int tid = threadIdx.x;
    int rg = blockIdx.x;                   // 0..63
    int cc = blockIdx.y;                   // 0..15
    int n = rg >> 4, h4 = rg & 15;
    int wid = tid >> 6, lane = tid & 63;
    int h = h4 * 4 + wid;
    int c0 = cc * CCH;

    for (int i = tid; i < KCH * RANK; i += 256) pdl[i] = pd[(size_t)c0 * 9 * RANK + i];

    int t = (n << 12) + (h << 6) + lane;
    float s = sx[t];
    const float* xrow = x + ((size_t)(n * C_INC) + c0) * 4096 + (h << 6) + lane;
    bool hok0 = (h > 0), hok2 = (h < 63);
    bool wok0 = (lane > 0), wok2 = (lane < 63);

    float acc[RANK];
    #pragma unroll
    for (int j = 0; j < RANK; ++j) acc[j] = 0.f;

    __syncthreads();   // pdl ready

    for (int cl = 0; cl < CCH; ++cl) {
        if (cl == 12) {
            // flush channels 0..11: 108 bytes = 27 dwords per token row
            __syncthreads();
            int bt = (n << 12) + (h4 << 8);
            for (int i = tid; i < 256 * 27; i += 256) {
                int row = i / 27, col = i - row * 27;
                *(unsigned int*)&qx[(size_t)(bt + row) * KPAD + cc * KCH + col * 4] =
                    *(unsigned int*)&qbuf[row * QSTR + col * 4];
            }
            __syncthreads();
        }
        const float* xc = xrow + (size_t)cl * 4096;
        float v[9];
        v[0] = (hok0 && wok0) ? xc[-65] : 0.f;
        v[1] =  hok0          ? xc[-64] : 0.f;
        v[2] = (hok0 && wok2) ? xc[-63] : 0.f;
        v[3] =  wok0          ? xc[-1]  : 0.f;
        v[4] =                  xc[0];
        v[5] =  wok2          ? xc[1]   : 0.f;
        v[6] = (hok2 && wok0) ? xc[63]  : 0.f;
        v[7] =  hok2          ? xc[64]  : 0.f;
        v[8] = (hok2 && wok2) ? xc[65]  : 0.f;
        int klbase = (cl < 12) ? cl * 9 : (cl - 12) * 9;
        #pragma unroll
        for (int u = 0; u < 9; ++u) {
            float q = rintf(v[u] / s);        // IEEE div for exact match
            q = fminf(fmaxf(q, -8.f), 7.f);
            qbuf[tid * QSTR + klbase + u] = (int8_t)q;
            const float4* p4 = (const float4*)&pdl[(cl * 9 + u) * RANK];
            #pragma unroll
            for (int jj = 0; jj < 8; ++jj) {
                float4 pv = p4[jj];
                acc[jj * 4 + 0] = fmaf(v[u], pv.x, acc[jj * 4 + 0]);
                acc[jj * 4 + 1] = fmaf(v[u], pv.y, acc[jj * 4 + 1]);
                acc[jj * 4 + 2] = fmaf(v[u], pv.z, acc[jj * 4 + 2]);
                acc[jj * 4 + 3] = fmaf(v[u], pv.w, acc[jj * 4 + 3]);
            }
        }
    }

    // store rpart partials as fp16 (native converts)
    {
        union { __half hh[RANK]; uint4 u4[4]; } pk;
        #pragma unroll
        for (int j = 0; j < RANK; ++j) pk.hh[j] = __float2half_rn(acc[j]);
        uint4* rp = (uint4*)(rpart + ((size_t)cc * NTOK + t) * RANK);
        rp[0] = pk.u4[0]; rp[1] = pk.u4[1]; rp[2] = pk.u4[2]; rp[3] = pk.u4[3];
    }

    // flush channels 12..19: 72 bytes = 18 dwords (+16 zero dwords pad on cc==15)
    __syncthreads();
    int bt = (n << 12) + (h4 << 8);
    if (cc == NCH - 1) {
        for (int i = tid; i < 256 * 34; i += 256) {
            int row = i / 34, col = i - row * 34;
            unsigned int vdw = (col < 18) ? *(unsigned int*)&qbuf[row * QSTR + col * 4] : 0u;
            *(unsigned int*)&qx[(size_t)(bt + row) * KPAD + cc * KCH + 108 + col * 4] = vdw;
        }
    } else {
        for (int i = tid; i < 256 * 18; i += 256) {
            int row = i / 18, col = i - row * 18;
            *(unsigned int*)&qx[(size_t)(bt + row) * KPAD + cc * KCH + 108 + col * 4] =
                *(unsigned int*)&qbuf[row * QSTR + col * 4];
        }
    }
}

// ---------------- int8 MFMA GEMM (R1 verbatim: 128x128, grid (128,3)) ----------------
__global__ __launch_bounds__(256) void k_gemm(const int8_t* __restrict__ qx,
                                              const int8_t* __restrict__ qw,
                                              const float* __restrict__ sx,
                                              const float* __restrict__ sw,
                                              float* __restrict__ out) {
    __shared__ int8_t lsA[128 * 80];
    __shared__ int8_t lsB[128 * 80];
    int tid = threadIdx.x;
    int m0 = blockIdx.x * 128;
    int n0 = blockIdx.y * 128;
    int wid = tid >> 6, lane = tid & 63;
    int wr = wid >> 1, wc = wid & 1;
    int lg = lane >> 4, lr = lane & 15;
    vi4 acc[4][4];
    #pragma unroll
    for (int i = 0; i < 4; ++i)
        #pragma unroll
        for (int j = 0; j < 4; ++j) acc[i][j] = (vi4)0;

    for (int kk = 0; kk < KPAD; kk += 64) {
        #pragma unroll
        for (int i = 0; i < 2; ++i) {
            int chunk = tid + i * 256;        // 0..511 chunks of 16B
            int row = chunk >> 2, c4 = chunk & 3;
            *(vi4*)&lsA[row * 80 + c4 * 16] =
                *(const vi4*)&qx[(size_t)(m0 + row) * KPAD + kk + c4 * 16];
            *(vi4*)&lsB[row * 80 + c4 * 16] =
                *(const vi4*)&qw[(size_t)(n0 + row) * KPAD + kk + c4 * 16];
        }
        __syncthreads();
        vi4 af[4], bf[4];
        #pragma unroll
        for (int mi = 0; mi < 4; ++mi)
            af[mi] = *(vi4*)&lsA[(wr * 64 + mi * 16 + lr) * 80 + lg * 16];
        #pragma unroll
        for (int ni = 0; ni < 4; ++ni)
            bf[ni] = *(vi4*)&lsB[(wc * 64 + ni * 16 + lr) * 80 + lg * 16];
        #pragma unroll
        for (int mi = 0; mi < 4; ++mi)
            #pragma unroll
            for (int ni = 0; ni < 4; ++ni)
                acc[mi][ni] = __builtin_amdgcn_mfma_i32_16x16x64_i8(af[mi], bf[ni], acc[mi][ni], 0, 0, 0);
        __syncthreads();
    }

    float swv[4];
    #pragma unroll
    for (int ni = 0; ni < 4; ++ni) swv[ni] = sw[n0 + wc * 64 + ni * 16 + lr];
    #pragma unroll
    for (int mi = 0; mi < 4; ++mi) {
        int rbase = m0 + wr * 64 + mi * 16 + lg * 4;
        #pragma unroll
        for (int r = 0; r < 4; ++r) {
            int row = rbase + r;
            float sxv = sx[row];
            #pragma unroll
            for (int ni = 0; ni < 4; ++ni) {
                int col = n0 + wc * 64 + ni * 16 + lr;
                out[(size_t)row * OUT_F + col] = ((float)acc[mi][ni][r] * sxv) * swv[ni];
            }
        }
    }
}

// ---------------- epilogue: out += (sum_cc rpart) @ up + bias ----------------
__global__ __launch_bounds__(384) void k_epi(float* __restrict__ out,
                                             const __half* __restrict__ rpart,
                                             const float* __restrict__ up,
                                             const float* __restrict__ bias) {
    __shared__ float upl[RANK * OUT_F];   // 48 KB
    __shared__ float rs[32][RANK];        // 4 KB
    int tid = threadIdx.x;                // 0..383
    for (int i = tid; i < RANK * OUT_F; i += 384) upl[i] = up[i];
    int t0 = blockIdx.x * 32;
    for (int i = tid; i < 32 * RANK; i += 384) {
        int tt = i >> 5, j = i & 31;
        float s = 0.f;
        #pragma unroll
        for (int cc = 0; cc < NCH; ++cc)
            s += __half2float(rpart[((size_t)cc * NTOK + t0 + tt) * RANK + j]);
        rs[tt][j] = s;
    }
    __syncthreads();
    int o = tid;
    float b = bias[o];
    for (int tt = 0; tt < 32; ++tt) {
        int t = t0 + tt;
        float a = out[(size_t)t * OUT_F + o];
        float l = 0.f;
        #pragma unroll
        for (int j = 0; j < RANK; ++j) l = fmaf(rs[tt][j], upl[j * OUT_F + o], l);
        out[(size_t)t * OUT_F + o] = a + l + b;
    }
}

extern "C" void kernel_launch(void* const* d_in, const int* in_sizes, int n_in,
                              void* d_out, int out_size, void* d_ws, size_t ws_size,
                              hipStream_t stream) {
    const float* x    = (const float*)d_in[0];
    const float* w    = (const float*)d_in[1];
    const float* pd   = (const float*)d_in[2];
    const float* pu   = (const float*)d_in[3];
    const float* bias = (const float*)d_in[4];
    float* out = (float*)d_out;

    char* ws = (char*)d_ws;
    int8_t* qw    = (int8_t*)(ws + 0);           // 1,130,496
    float*  sw    = (float*) (ws + 1130496);     // 1,536
    float*  mb    = (float*) (ws + 1132032);     // 65,536
    float*  sx    = (float*) (ws + 1197568);     // 65,536
    int8_t* qx    = (int8_t*)(ws + 1263104);     // 48,234,496
    __half* rpart = (__half*)(ws + 49497600);    // 16*16384*32*2 = 16,777,216 (end 66,274,816)

    hipLaunchKernelGGL(kq_w,    dim3(OUT_F),   dim3(256), 0, stream, w, qw, sw);
    hipLaunchKernelGGL(k_chmax, dim3(64),      dim3(256), 0, stream, x, mb);
    hipLaunchKernelGGL(k_sx,    dim3(64),      dim3(256), 0, stream, mb, sx);
    hipLaunchKernelGGL(k_fused, dim3(64, NCH), dim3(256), 0, stream, x, pd, sx, qx, rpart);
    hipLaunchKernelGGL(k_gemm,  dim3(128, 3),  dim3(256), 0, stream, qx, qw, sx, sw, out);
    hipLaunchKernelGGL(k_epi,   dim3(512),     dim3(384), 0, stream, out, rpart, pu, bias);
}

// Round 5
// 236.026 us; speedup vs baseline: 1.5145x; 1.1952x over previous
//
#include <hip/hip_runtime.h>
#include <hip/hip_fp16.h>
#include <stdint.h>
#include <stddef.h>

#define C_INC 320
#define KREAL 2880
#define KPAD  2944
#define OUT_F 384
#define RANK  32
#define HH    64
#define WW    64
#define NTOK  16384
#define NCH   16         // channel chunks for fused kernel
#define CCH   20         // channels per chunk (16*20=320)
#define QSTR  76         // qbuf row stride bytes (max 8ch*9=72 +4 pad; 19 words, gcd(19,32)=1)

typedef int vi4 __attribute__((ext_vector_type(4)));

// ---------------- quantize weights per output row (exact IEEE div) ----------------
__global__ __launch_bounds__(256) void kq_w(const float* __restrict__ w,
                                            int8_t* __restrict__ qw,
                                            float* __restrict__ sw) {
    int o = blockIdx.x;
    const float* row = w + (size_t)o * KPAD;
    float m = 0.f;
    for (int k = threadIdx.x; k < KPAD; k += 256) m = fmaxf(m, fabsf(row[k]));
    #pragma unroll
    for (int off = 32; off > 0; off >>= 1) m = fmaxf(m, __shfl_down(m, off, 64));
    __shared__ float red[4];
    __shared__ float sval;
    if ((threadIdx.x & 63) == 0) red[threadIdx.x >> 6] = m;
    __syncthreads();
    if (threadIdx.x == 0) {
        float mm = fmaxf(fmaxf(red[0], red[1]), fmaxf(red[2], red[3]));
        sval = fmaxf(mm / 7.0f, 1e-8f);
        sw[o] = sval;
    }
    __syncthreads();
    float s = sval;
    for (int k = threadIdx.x; k < KPAD; k += 256) {
        float q = rintf(row[k] / s);          // IEEE div + RNE, matches np
        q = fminf(fmaxf(q, -8.f), 7.f);
        qw[(size_t)o * KPAD + k] = (int8_t)q;
    }
}

// ---------------- per-pixel channel abs-max, channel-split (512 blocks) ----------------
__global__ __launch_bounds__(256) void k_chmax(const float* __restrict__ x,
                                               float* __restrict__ mb2) {
    int p = blockIdx.x * 256 + threadIdx.x;   // 0..16383
    int cc = blockIdx.y;                       // 0..7
    int n = p >> 12, hw = p & 4095;
    const float* base = x + ((size_t)(n * C_INC) + cc * 40) * 4096 + hw;
    float m = 0.f;
    #pragma unroll 4
    for (int c = 0; c < 40; ++c) m = fmaxf(m, fabsf(base[(size_t)c * 4096]));
    mb2[(size_t)cc * NTOK + p] = m;
}

// ---------------- sx = max over 3x3 neighborhood of 8 planes / 7 ----------------
__global__ __launch_bounds__(256) void k_sx(const float* __restrict__ mb2,
                                            float* __restrict__ sx) {
    int p = blockIdx.x * 256 + threadIdx.x;
    int n = p >> 12, hw = p & 4095;
    int h = hw >> 6, w = hw & 63;
    float m = 0.f;
    #pragma unroll
    for (int cc = 0; cc < 8; ++cc) {
        const float* pl = mb2 + (size_t)cc * NTOK + (n << 12);
        #pragma unroll
        for (int di = -1; di <= 1; ++di)
            #pragma unroll
            for (int dj = -1; dj <= 1; ++dj) {
                int hh = h + di, ww = w + dj;
                if ((unsigned)hh < (unsigned)HH && (unsigned)ww < (unsigned)WW)
                    m = fmaxf(m, pl[(hh << 6) + ww]);
            }
    }
    sx[p] = fmaxf(m / 7.0f, 1e-8f);
}

// ---------------- fused im2col quantize + LoRA down-projection ----------------
// grid (64, 16). One wave per image row (lane = w); neighbors via direct
// predicated global loads (no shfl — see R4). 3 phases of {8,8,4} channels
// with per-phase pdl staging: LDS 28.7 KB -> 4 blocks/CU (grid-limited).
// Per-token reciprocal hoisted out of the quantize loop (1 div/lane).
__global__ __launch_bounds__(256) void k_fused(const float* __restrict__ x,
                                               const float* __restrict__ pd,
                                               const float* __restrict__ sx,
                                               int8_t* __restrict__ qx,
                                               __half* __restrict__ rpart) {
    __shared__ float  pdl[8 * 9 * RANK];   // 9216 B (max phase: 8 channels)
    __shared__ int8_t qbuf[256 * QSTR];    // 19456 B
    const int pstart[4] = {0, 8, 16, 20};  // phase channel starts (sizes 8,8,4)
    const int phoff[3]  = {0, 72, 144};    // byte offset within this chunk's k-range

    int tid = threadIdx.x;
    int rg = blockIdx.x;                   // 0..63
    int cc = blockIdx.y;                   // 0..15
    int n = rg >> 4, h4 = rg & 15;
    int wid = tid >> 6, lane = tid & 63;
    int h = h4 * 4 + wid;
    int c0 = cc * CCH;

    int t = (n << 12) + (h << 6) + lane;
    float s = sx[t];
    float inv = 1.0f / s;                  // one exact div per lane
    const float* xrow = x + ((size_t)(n * C_INC) + c0) * 4096 + (h << 6) + lane;
    bool hok0 = (h > 0), hok2 = (h < 63);
    bool wok0 = (lane > 0), wok2 = (lane < 63);
    int bt = (n << 12) + (h4 << 8);

    float acc[RANK];
    #pragma unroll
    for (int j = 0; j < RANK; ++j) acc[j] = 0.f;

    for (int ph = 0; ph < 3; ++ph) {
        int ps = pstart[ph], pe = pstart[ph + 1], pch = pe - ps;
        __syncthreads();   // prior phase's pdl reads + qbuf writes complete
        // flush previous phase's qbuf to global
        if (ph > 0) {
            int ndw = (ph == 1) ? 18 : 18;   // phases 0 and 1 are both 8 ch = 18 dwords
            for (int i = tid; i < 256 * 18; i += 256) {
                int row = i / 18, col = i - row * 18;
                *(unsigned int*)&qx[(size_t)(bt + row) * KPAD + cc * 180 + phoff[ph - 1] + col * 4] =
                    *(unsigned int*)&qbuf[row * QSTR + col * 4];
            }
            (void)ndw;
        }
        // stage this phase's pd slice
        for (int i = tid; i < pch * 9 * RANK; i += 256)
            pdl[i] = pd[((size_t)(c0 + ps) * 9) * RANK + i];
        __syncthreads();   // pdl ready, flush done

        for (int cl = 0; cl < pch; ++cl) {
            const float* xc = xrow + (size_t)(ps + cl) * 4096;
            float v[9];
            v[0] = (hok0 && wok0) ? xc[-65] : 0.f;
            v[1] =  hok0          ? xc[-64] : 0.f;
            v[2] = (hok0 && wok2) ? xc[-63] : 0.f;
            v[3] =  wok0          ? xc[-1]  : 0.f;
            v[4] =                  xc[0];
            v[5] =  wok2          ? xc[1]   : 0.f;
            v[6] = (hok2 && wok0) ? xc[63]  : 0.f;
            v[7] =  hok2          ? xc[64]  : 0.f;
            v[8] = (hok2 && wok2) ? xc[65]  : 0.f;
            #pragma unroll
            for (int u = 0; u < 9; ++u) {
                float q = rintf(v[u] * inv);
                q = fminf(fmaxf(q, -8.f), 7.f);
                qbuf[tid * QSTR + cl * 9 + u] = (int8_t)q;
                const float4* p4 = (const float4*)&pdl[(cl * 9 + u) * RANK];
                #pragma unroll
                for (int jj = 0; jj < 8; ++jj) {
                    float4 pv = p4[jj];
                    acc[jj * 4 + 0] = fmaf(v[u], pv.x, acc[jj * 4 + 0]);
                    acc[jj * 4 + 1] = fmaf(v[u], pv.y, acc[jj * 4 + 1]);
                    acc[jj * 4 + 2] = fmaf(v[u], pv.z, acc[jj * 4 + 2]);
                    acc[jj * 4 + 3] = fmaf(v[u], pv.w, acc[jj * 4 + 3]);
                }
            }
        }
    }

    // store rpart partials as fp16
    {
        union { __half hh[RANK]; uint4 u4[4]; } pk;
        #pragma unroll
        for (int j = 0; j < RANK; ++j) pk.hh[j] = __float2half_rn(acc[j]);
        uint4* rp = (uint4*)(rpart + ((size_t)cc * NTOK + t) * RANK);
        rp[0] = pk.u4[0]; rp[1] = pk.u4[1]; rp[2] = pk.u4[2]; rp[3] = pk.u4[3];
    }

    // flush phase 2 (4 ch = 9 dwords; cc==15 adds 16 zero dwords for k-pad)
    __syncthreads();
    if (cc == NCH - 1) {
        for (int i = tid; i < 256 * 25; i += 256) {
            int row = i / 25, col = i - row * 25;
            unsigned int vdw = (col < 9) ? *(unsigned int*)&qbuf[row * QSTR + col * 4] : 0u;
            *(unsigned int*)&qx[(size_t)(bt + row) * KPAD + cc * 180 + 144 + col * 4] = vdw;
        }
    } else {
        for (int i = tid; i < 256 * 9; i += 256) {
            int row = i / 9, col = i - row * 9;
            *(unsigned int*)&qx[(size_t)(bt + row) * KPAD + cc * 180 + 144 + col * 4] =
                *(unsigned int*)&qbuf[row * QSTR + col * 4];
        }
    }
}

// ---------------- int8 MFMA GEMM (R1 verbatim: 128x128, grid (128,3)) ----------------
__global__ __launch_bounds__(256) void k_gemm(const int8_t* __restrict__ qx,
                                              const int8_t* __restrict__ qw,
                                              const float* __restrict__ sx,
                                              const float* __restrict__ sw,
                                              float* __restrict__ out) {
    __shared__ int8_t lsA[128 * 80];
    __shared__ int8_t lsB[128 * 80];
    int tid = threadIdx.x;
    int m0 = blockIdx.x * 128;
    int n0 = blockIdx.y * 128;
    int wid = tid >> 6, lane = tid & 63;
    int wr = wid >> 1, wc = wid & 1;
    int lg = lane >> 4, lr = lane & 15;
    vi4 acc[4][4];
    #pragma unroll
    for (int i = 0; i < 4; ++i)
        #pragma unroll
        for (int j = 0; j < 4; ++j) acc[i][j] = (vi4)0;

    for (int kk = 0; kk < KPAD; kk += 64) {
        #pragma unroll
        for (int i = 0; i < 2; ++i) {
            int chunk = tid + i * 256;        // 0..511 chunks of 16B
            int row = chunk >> 2, c4 = chunk & 3;
            *(vi4*)&lsA[row * 80 + c4 * 16] =
                *(const vi4*)&qx[(size_t)(m0 + row) * KPAD + kk + c4 * 16];
            *(vi4*)&lsB[row * 80 + c4 * 16] =
                *(const vi4*)&qw[(size_t)(n0 + row) * KPAD + kk + c4 * 16];
        }
        __syncthreads();
        vi4 af[4], bf[4];
        #pragma unroll
        for (int mi = 0; mi < 4; ++mi)
            af[mi] = *(vi4*)&lsA[(wr * 64 + mi * 16 + lr) * 80 + lg * 16];
        #pragma unroll
        for (int ni = 0; ni < 4; ++ni)
            bf[ni] = *(vi4*)&lsB[(wc * 64 + ni * 16 + lr) * 80 + lg * 16];
        #pragma unroll
        for (int mi = 0; mi < 4; ++mi)
            #pragma unroll
            for (int ni = 0; ni < 4; ++ni)
                acc[mi][ni] = __builtin_amdgcn_mfma_i32_16x16x64_i8(af[mi], bf[ni], acc[mi][ni], 0, 0, 0);
        __syncthreads();
    }

    float swv[4];
    #pragma unroll
    for (int ni = 0; ni < 4; ++ni) swv[ni] = sw[n0 + wc * 64 + ni * 16 + lr];
    #pragma unroll
    for (int mi = 0; mi < 4; ++mi) {
        int rbase = m0 + wr * 64 + mi * 16 + lg * 4;
        #pragma unroll
        for (int r = 0; r < 4; ++r) {
            int row = rbase + r;
            float sxv = sx[row];
            #pragma unroll
            for (int ni = 0; ni < 4; ++ni) {
                int col = n0 + wc * 64 + ni * 16 + lr;
                out[(size_t)row * OUT_F + col] = ((float)acc[mi][ni][r] * sxv) * swv[ni];
            }
        }
    }
}

// ---------------- epilogue: out += (sum_cc rpart) @ up + bias ----------------
__global__ __launch_bounds__(384) void k_epi(float* __restrict__ out,
                                             const __half* __restrict__ rpart,
                                             const float* __restrict__ up,
                                             const float* __restrict__ bias) {
    __shared__ float upl[RANK * OUT_F];   // 48 KB
    __shared__ float rs[32][RANK];        // 4 KB
    int tid = threadIdx.x;                // 0..383
    for (int i = tid; i < RANK * OUT_F; i += 384) upl[i] = up[i];
    int t0 = blockIdx.x * 32;
    for (int i = tid; i < 32 * RANK; i += 384) {
        int tt = i >> 5, j = i & 31;
        float s = 0.f;
        #pragma unroll
        for (int cc = 0; cc < NCH; ++cc)
            s += __half2float(rpart[((size_t)cc * NTOK + t0 + tt) * RANK + j]);
        rs[tt][j] = s;
    }
    __syncthreads();
    int o = tid;
    float b = bias[o];
    for (int tt = 0; tt < 32; ++tt) {
        int t = t0 + tt;
        float a = out[(size_t)t * OUT_F + o];
        float l = 0.f;
        #pragma unroll
        for (int j = 0; j < RANK; ++j) l = fmaf(rs[tt][j], upl[j * OUT_F + o], l);
        out[(size_t)t * OUT_F + o] = a + l + b;
    }
}

extern "C" void kernel_launch(void* const* d_in, const int* in_sizes, int n_in,
                              void* d_out, int out_size, void* d_ws, size_t ws_size,
                              hipStream_t stream) {
    const float* x    = (const float*)d_in[0];
    const float* w    = (const float*)d_in[1];
    const float* pd   = (const float*)d_in[2];
    const float* pu   = (const float*)d_in[3];
    const float* bias = (const float*)d_in[4];
    float* out = (float*)d_out;

    char* ws = (char*)d_ws;
    int8_t* qw    = (int8_t*)(ws + 0);           // 1,130,496
    float*  sw    = (float*) (ws + 1130496);     // 1,536
    float*  mb2   = (float*) (ws + 1132032);     // 8*16384*4 = 524,288
    float*  sx    = (float*) (ws + 1656320);     // 65,536
    int8_t* qx    = (int8_t*)(ws + 1721856);     // 48,234,496
    __half* rpart = (__half*)(ws + 49956352);    // 16*16384*32*2 = 16,777,216 (end 66,733,568)

    hipLaunchKernelGGL(kq_w,    dim3(OUT_F),   dim3(256), 0, stream, w, qw, sw);
    hipLaunchKernelGGL(k_chmax, dim3(64, 8),   dim3(256), 0, stream, x, mb2);
    hipLaunchKernelGGL(k_sx,    dim3(64),      dim3(256), 0, stream, mb2, sx);
    hipLaunchKernelGGL(k_fused, dim3(64, NCH), dim3(256), 0, stream, x, pd, sx, qx, rpart);
    hipLaunchKernelGGL(k_gemm,  dim3(128, 3),  dim3(256), 0, stream, qx, qw, sx, sw, out);
    hipLaunchKernelGGL(k_epi,   dim3(512),     dim3(384), 0, stream, out, rpart, pu, bias);
}